// Round 1
// baseline (221.440 us; speedup 1.0000x reference)
//
#include <hip/hip_runtime.h>

#define NLAYER 4
#define BATCH  256
#define HID    1024

typedef float f32x4 __attribute__((ext_vector_type(4)));
typedef short short8 __attribute__((ext_vector_type(8)));
typedef unsigned short ushort_t;
typedef unsigned long long u64;

// Raw sync primitives (round-4 proven discipline). All counted VM ops (GLD16 /
// GLDB asm) and WAITV/BAR are volatile -> mutual program order. Register ties
// ("+v") keep consumers from hoisting above the waitcnt (rule #18).
#define BAR()     asm volatile("s_barrier")
#define WAITV_TIE2(n, x, y) \
  asm volatile("s_waitcnt vmcnt(" #n ")" : "+v"(x), "+v"(y))
#define WAITV_TIE4(n, x, y, z, u) \
  asm volatile("s_waitcnt vmcnt(" #n ")" : "+v"(x), "+v"(y), "+v"(z), "+v"(u))
#define DSR(d, a) asm volatile("ds_read_b128 %0, %1" : "=v"(d) : "v"(a))
#define DSW(a, d) asm volatile("ds_write_b128 %0, %1" :: "v"(a), "v"(d))
#define LGKM0()   asm volatile("s_waitcnt lgkmcnt(0)")
#define LGKM0_TIE4(a,b,c,d) \
  asm volatile("s_waitcnt lgkmcnt(0)" : "+v"(a),"+v"(b),"+v"(c),"+v"(d))
#define FULLBAR() asm volatile("s_waitcnt vmcnt(0) lgkmcnt(0)\ns_barrier" ::: "memory")
#define GLD16(d, a) asm volatile("global_load_dwordx4 %0, %1, off" : "=v"(d) : "v"(a))
// two 16B loads at a, a+16; early-clobber so dests never alias the addr pair
#define GLDB(d0, d1, a) asm volatile( \
    "global_load_dwordx4 %0, %2, off\n\t" \
    "global_load_dwordx4 %1, %2, off offset:16" \
    : "=&v"(d0), "=&v"(d1) : "v"(a))

__device__ __forceinline__ unsigned short f2bf(float f) {
  unsigned int u = __float_as_uint(f);
  unsigned int r = u + 0x7fffu + ((u >> 16) & 1u);  // RNE
  return (unsigned short)(r >> 16);
}
__device__ __forceinline__ float sigm(float x) { return 1.f / (1.f + __expf(-x)); }
__device__ __forceinline__ float tanh_(float x) { return 2.f / (1.f + __expf(-2.f * x)) - 1.f; }

__device__ __forceinline__ short8 cvt8(f32x4 a, f32x4 b) {
  short8 p;
  p[0] = (short)f2bf(a[0]); p[1] = (short)f2bf(a[1]);
  p[2] = (short)f2bf(a[2]); p[3] = (short)f2bf(a[3]);
  p[4] = (short)f2bf(b[0]); p[5] = (short)f2bf(b[1]);
  p[6] = (short)f2bf(b[2]); p[7] = (short)f2bf(b[3]);
  return p;
}

// Packed tile format (64x64 tile = 8KB): logical (r 0..63, c 0..7 16B-chunks)
// at chunk = (r>>3)*64 + (r&7)*8 + ((c^r)&7). Same as rounds 3-5. Now this
// layout exists ONLY in LDS (built in-kernel from fp32 W) and in apk.

// ---- pack A (unchanged): layer0 kt0..15 from x; kt16..31 from h0[l] ----
__global__ __launch_bounds__(256) void pack_a(const float* __restrict__ x,
                                              const float* __restrict__ h0,
                                              ushort_t* __restrict__ apk) {
  int t = blockIdx.x * 256 + threadIdx.x;  // 0..163839
  int lane = t & 63;
  int r8 = lane >> 3;
  int c = (lane & 7) ^ r8;
  const float* src;
  ushort_t* dst;
  if (t < 32768) {
    int g = (t >> 6) & 7, kt = (t >> 9) & 15, mb = t >> 13;
    int m = mb * 64 + g * 8 + r8;
    src = x + (size_t)m * 1024 + kt * 64 + c * 8;
    dst = apk + (size_t)mb * 131072 + (size_t)kt * 4096 + g * 512 + lane * 8;
  } else {
    int u = t - 32768;
    int g = (u >> 6) & 7, kt16 = (u >> 9) & 15, mb = (u >> 13) & 3, l = u >> 15;
    int m = mb * 64 + g * 8 + r8;
    src = h0 + (size_t)l * 262144 + (size_t)m * 1024 + kt16 * 64 + c * 8;
    dst = apk + (size_t)l * 524288 + (size_t)mb * 131072
        + (size_t)(16 + kt16) * 4096 + g * 512 + lane * 8;
  }
  float4 a = *(const float4*)src, b = *(const float4*)(src + 4);
  short8 pk;
  pk[0] = (short)f2bf(a.x); pk[1] = (short)f2bf(a.y);
  pk[2] = (short)f2bf(a.z); pk[3] = (short)f2bf(a.w);
  pk[4] = (short)f2bf(b.x); pk[5] = (short)f2bf(b.y);
  pk[6] = (short)f2bf(b.z); pk[7] = (short)f2bf(b.w);
  *(short8*)dst = pk;
}

// ---- fused layer GEMM v3: B read as fp32 DIRECT from w_ih/w_hh (no pack_w
// pre-pass), converted to bf16 in-register, ds_write'd into the same swizzled
// quad-buffered 8KB tiles. A-frags gathered from L2 (4 rotating reg slots,
// 3 ahead). Per iter issue [B(kt+3)x2, A(kt+3)x2]; WAITV(6) before use =>
// B(kt+1) in regs (convert+write this iter) and A(kt) in regs (MFMA this
// iter). One ds_write->lgkm0->barrier per iter. LSTM cell epilogue. ----
__global__ __launch_bounds__(512) void lstm_fused(
    const ushort_t* __restrict__ apk,
    const float* __restrict__ wih, const float* __restrict__ whh,
    const float* __restrict__ bi, const float* __restrict__ bh,
    const float* __restrict__ c0l,
    float* __restrict__ hout, float* __restrict__ cout,
    ushort_t* __restrict__ apk_next) {
  __shared__ union U {
    ushort_t stage[4][4096];   // 4 x 8KB B tiles
    float sg[4 * 64 * 17];     // epilogue gate exchange (17.4KB, fits)
  } sm;

  const int tid = threadIdx.x;
  const int nb = blockIdx.x;   // 0..63
  const int mb = blockIdx.y;   // 0..3
  const int h0c = nb * 16;
  const int m0 = mb * 64;
  const int lane = tid & 63;
  const int w = tid >> 6;
  const int wm = w & 3, wcol = w >> 2;
  const int lrow = lane & 15, lq = lane >> 4;

#define CHUNK(r, c) (((r) >> 3) * 64 + ((r) & 7) * 8 + (((c) ^ (r)) & 7))
  // A gather addresses (bytes), advance 8192/tile
  const int rA = wm * 16 + lrow;
  u64 aA0 = (u64)(const char*)(apk + (size_t)mb * 131072 + CHUNK(rA, lq) * 8);
  u64 aA1 = (u64)(const char*)(apk + (size_t)mb * 131072 + CHUNK(rA, 4 + lq) * 8);

  // B fp32 gather: thread owns packed chunk (rW, cW) of each tile.
  // tile row rW -> W row gate*1024 + nb*16 + (rW&15); chunk cW -> k cW*8..+7.
  const int rW = tid >> 3, cW = tid & 7;
  const int gate = rW >> 4;
  const size_t wroff = (size_t)(gate * 1024 + nb * 16 + (rW & 15)) * 1024 + cW * 8;
  u64 aB  = (u64)(const char*)(wih + wroff);
  u64 hhA = (u64)(const char*)(whh + wroff);

  // LDS addresses
  unsigned smb = (unsigned)(uintptr_t)(__attribute__((address_space(3))) void*)&sm;
  unsigned dsw = smb + CHUNK(rW, cW) * 16;                 // my write chunk
  const int rB0 = wcol * 32 + lrow, rB1 = rB0 + 16;        // frag reads
  unsigned oB00 = smb + CHUNK(rB0, lq) * 16, oB01 = smb + CHUNK(rB0, 4 + lq) * 16;
  unsigned oB10 = smb + CHUNK(rB1, lq) * 16, oB11 = smb + CHUNK(rB1, 4 + lq) * 16;
#undef CHUNK

  f32x4 acc0 = {0.f, 0.f, 0.f, 0.f}, acc1 = {0.f, 0.f, 0.f, 0.f};
  short8 areg[4][2];
  f32x4 breg[4][2];
  int tIss = 3;

  // prologue: issue tiles 0,1,2 (all from w_ih); per tile order Ba,Bb,Aa,Ab
#pragma unroll
  for (int t = 0; t < 3; ++t) {
    GLDB(breg[t][0], breg[t][1], aB); aB += 256;
    GLD16(areg[t][0], aA0); aA0 += 8192;
    GLD16(areg[t][1], aA1); aA1 += 8192;
  }
  // land B(0) (10 newer ops outstanding), build LDS tile 0
  WAITV_TIE2(10, breg[0][0], breg[0][1]);
  {
    short8 p0 = cvt8(breg[0][0], breg[0][1]);
    DSW(dsw, p0);
  }
  LGKM0();
  BAR();

  // Per iter kt (slot S=kt&3): WAITV(PRE) => B(kt+1)+A(kt) landed; issue tile
  // kt+3 (slot S3, its old B consumed at kt-2, A at kt-1); convert+write tile
  // kt+1 (slot S1, last read as tile kt-3 two barriers ago); lgkm0+BAR; read
  // tile kt (written last iter, 1 barrier ago); MFMA. Steady PRE=6: newest 6
  // in flight = {A(kt+1)x2, B(kt+2)x2, A(kt+2)x2}.
#define KSTEP(S, PRE, ISSUE, CONV)                                          \
  {                                                                         \
    const int S1 = ((S) + 1) & 3, S3 = ((S) + 3) & 3;                       \
    WAITV_TIE4(PRE, breg[S1][0], breg[S1][1], areg[S][0], areg[S][1]);      \
    if (ISSUE) {                                                            \
      GLDB(breg[S3][0], breg[S3][1], aB);                                   \
      ++tIss;                                                               \
      aB = (tIss == 16) ? hhA : (aB + 256);  /* w_ih -> w_hh at tile 16 */  \
      GLD16(areg[S3][0], aA0); aA0 += 8192;                                 \
      GLD16(areg[S3][1], aA1); aA1 += 8192;                                 \
    }                                                                       \
    if (CONV) {                                                             \
      short8 pk_ = cvt8(breg[S1][0], breg[S1][1]);                          \
      DSW(dsw + (unsigned)(S1) * 8192u, pk_);                               \
    }                                                                       \
    LGKM0();                                                                \
    BAR();                                                                  \
    short8 b00, b01, b10, b11;                                              \
    DSR(b00, oB00 + (S) * 8192u); DSR(b10, oB10 + (S) * 8192u);             \
    DSR(b01, oB01 + (S) * 8192u); DSR(b11, oB11 + (S) * 8192u);             \
    LGKM0_TIE4(b00, b01, b10, b11);                                         \
    acc0 = __builtin_amdgcn_mfma_f32_16x16x32_bf16(areg[S][0], b00, acc0, 0, 0, 0); \
    acc1 = __builtin_amdgcn_mfma_f32_16x16x32_bf16(areg[S][0], b10, acc1, 0, 0, 0); \
    acc0 = __builtin_amdgcn_mfma_f32_16x16x32_bf16(areg[S][1], b01, acc0, 0, 0, 0); \
    acc1 = __builtin_amdgcn_mfma_f32_16x16x32_bf16(areg[S][1], b11, acc1, 0, 0, 0); \
  }

  // kt = 0..27 (7 x 4, slots static), then peeled 28..31 with exact tail waits
  for (int i = 0; i < 7; ++i) {
    KSTEP(0, 6, 1, 1)
    KSTEP(1, 6, 1, 1)
    KSTEP(2, 6, 1, 1)
    KSTEP(3, 6, 1, 1)
  }
  KSTEP(0, 6, 1, 1)   // kt=28, issues tile 31
  KSTEP(1, 6, 0, 1)   // kt=29, converts tile 30; 6 = {A30x2, B31x2, A31x2}
  KSTEP(2, 2, 0, 1)   // kt=30, converts tile 31; 2 = {A31x2}
  KSTEP(3, 0, 0, 0)   // kt=31, drain
#undef KSTEP

  FULLBAR();  // vmcnt already 0; drain LDS, then overlay sg over stage

  // acc layout (verified): row = m0 + wm*16 + lq*4 + r, gate = wcol*2+nt, hcol = lrow
#pragma unroll
  for (int nt = 0; nt < 2; ++nt) {
    int gatee = wcol * 2 + nt;
    int rowb = wm * 16 + lq * 4;
    const f32x4& a = nt ? acc1 : acc0;
#pragma unroll
    for (int r = 0; r < 4; ++r)
      sm.sg[gatee * 1088 + (rowb + r) * 17 + lrow] = a[r];
  }
  FULLBAR();

  {
    const int erow = tid >> 3, ehp = (tid & 7) * 2;
    // epilogue-only global loads: issued after all counted VM ops (safe)
    float2 cp = *(const float2*)(c0l + (size_t)(m0 + erow) * 1024 + h0c + ehp);
    float cpa[2] = {cp.x, cp.y};
    float hva[2], cva[2];
#pragma unroll
    for (int e = 0; e < 2; ++e) {
      int hc = ehp + e;
      float gi = sm.sg[0 * 1088 + erow * 17 + hc] + bi[h0c + hc]          + bh[h0c + hc];
      float gf = sm.sg[1 * 1088 + erow * 17 + hc] + bi[1024 + h0c + hc]   + bh[1024 + h0c + hc];
      float gg = sm.sg[2 * 1088 + erow * 17 + hc] + bi[2048 + h0c + hc]   + bh[2048 + h0c + hc];
      float go = sm.sg[3 * 1088 + erow * 17 + hc] + bi[3072 + h0c + hc]   + bh[3072 + h0c + hc];
      float cn = sigm(gf) * cpa[e] + sigm(gi) * tanh_(gg);
      cva[e] = cn;
      hva[e] = sigm(go) * tanh_(cn);
    }
    float2 hv; hv.x = hva[0]; hv.y = hva[1];
    float2 cv; cv.x = cva[0]; cv.y = cva[1];
    *(float2*)(hout + (size_t)(m0 + erow) * 1024 + h0c + ehp) = hv;
    *(float2*)(cout + (size_t)(m0 + erow) * 1024 + h0c + ehp) = cv;
    if (apk_next) {  // packed bf16 h for next layer's A gathers
      int g = erow >> 3;
#pragma unroll
      for (int e = 0; e < 2; ++e) {
        int k = h0c + ehp + e;
        int cc = (k >> 3) & 7, j = k & 7;
        int i = (erow & 7) * 8 + ((cc ^ erow) & 7);
        apk_next[(size_t)mb * 131072 + (size_t)(k >> 6) * 4096 + g * 512 + i * 8 + j] =
            f2bf(hva[e]);
      }
    }
  }
}

extern "C" void kernel_launch(void* const* d_in, const int* in_sizes, int n_in,
                              void* d_out, int out_size, void* d_ws, size_t ws_size,
                              hipStream_t stream) {
  const float* x    = (const float*)d_in[0];
  const float* h0   = (const float*)d_in[1];
  const float* c0   = (const float*)d_in[2];
  const float* w_ih = (const float*)d_in[3];
  const float* w_hh = (const float*)d_in[4];
  const float* b_ih = (const float*)d_in[5];
  const float* b_hh = (const float*)d_in[6];
  float* out = (float*)d_out;

  ushort_t* Apk = (ushort_t*)d_ws;   // 4 layers x 1 MB packed bf16 activations

  pack_a<<<640, 256, 0, stream>>>(x, h0, Apk);

  const size_t BH = (size_t)BATCH * HID;
  for (int l = 0; l < NLAYER; ++l) {
    lstm_fused<<<dim3(64, 4), 512, 0, stream>>>(
        Apk + (size_t)l * 524288,
        w_ih + (size_t)l * 4194304, w_hh + (size_t)l * 4194304,
        b_ih + (size_t)l * 4096, b_hh + (size_t)l * 4096,
        c0 + (size_t)l * BH,
        out + (size_t)l * BH, out + (size_t)NLAYER * BH + (size_t)l * BH,
        (l < NLAYER - 1) ? Apk + (size_t)(l + 1) * 524288 : (ushort_t*)nullptr);
  }
}